// Round 1
// baseline (2420.126 us; speedup 1.0000x reference)
//
#include <hip/hip_runtime.h>

#define S_LEN 2048
#define B_SZ  64
#define D_IN  128
#define H_SZ  128
#define G4    512   // 4*H

typedef __attribute__((ext_vector_type(8))) short   short8;
typedef __attribute__((ext_vector_type(4))) float   floatx4;

// bf16 helpers (avoid hip_bf16 API differences; round-to-nearest-even)
__device__ __forceinline__ unsigned short f2bf(float f) {
  unsigned int u = __float_as_uint(f);
  u = (u + 0x7FFFu + ((u >> 16) & 1u)) >> 16;
  return (unsigned short)u;
}
__device__ __forceinline__ float bf2f(unsigned short s) {
  return __uint_as_float(((unsigned int)s) << 16);
}

// ---------------------------------------------------------------------------
// Kernel 1: gates_x[sb][n] = sum_k X[sb][k]*W_ih[n][k] + b[n], stored bf16.
// MFMA 16x16x32 bf16. Each WG: 64 rows x all 512 cols. W_ih staged to LDS in
// 4 chunks of 128 gate-rows (bf16, row padded 128->136 to break bank stride).
// ---------------------------------------------------------------------------
__global__ __launch_bounds__(256) void gx_gemm(
    const float* __restrict__ X,       // [S*B][128]
    const float* __restrict__ Wih,     // [512][128]
    const float* __restrict__ bias,    // [512]
    unsigned short* __restrict__ gx)   // [S*B][512] bf16
{
  __shared__ unsigned short Wl[128][136];
  const int tid  = threadIdx.x;
  const int lane = tid & 63;
  const int wv   = tid >> 6;           // wave 0..3
  const int R0   = blockIdx.x * 64;
  const int m    = lane & 15;
  const int q    = lane >> 4;          // quad 0..3

  // A-fragments: rows R0+wv*16+m of X, 4 K-chunks of 32 (lane holds 8 k)
  short8 afrag[4];
  const float* xrow = X + (size_t)(R0 + wv * 16 + m) * D_IN;
  #pragma unroll
  for (int kf = 0; kf < 4; ++kf) {
    const int k0 = kf * 32 + q * 8;
    floatx4 v0 = *(const floatx4*)(xrow + k0);
    floatx4 v1 = *(const floatx4*)(xrow + k0 + 4);
    short8 a;
    a[0] = (short)f2bf(v0.x); a[1] = (short)f2bf(v0.y);
    a[2] = (short)f2bf(v0.z); a[3] = (short)f2bf(v0.w);
    a[4] = (short)f2bf(v1.x); a[5] = (short)f2bf(v1.y);
    a[6] = (short)f2bf(v1.z); a[7] = (short)f2bf(v1.w);
    afrag[kf] = a;
  }

  for (int nc = 0; nc < 4; ++nc) {      // 4 chunks of 128 gate-rows
    __syncthreads();                    // protect Wl readers from restage
    // stage W_ih rows [nc*128, nc*128+128) as bf16 into LDS
    for (int i = tid; i < 128 * 32; i += 256) {   // float4 units
      const int row = i >> 5;
      const int c4  = (i & 31) * 4;
      floatx4 v = *(const floatx4*)(Wih + ((size_t)nc * 128 + row) * D_IN + c4);
      Wl[row][c4 + 0] = f2bf(v.x);
      Wl[row][c4 + 1] = f2bf(v.y);
      Wl[row][c4 + 2] = f2bf(v.z);
      Wl[row][c4 + 3] = f2bf(v.w);
    }
    __syncthreads();

    #pragma unroll
    for (int nt = 0; nt < 8; ++nt) {    // 8 n-tiles of 16 per chunk
      const int n0  = nc * 128 + nt * 16;   // global col base
      const int nlo = nt * 16 + m;          // local W row in chunk
      const float bv = bias[n0 + m];
      floatx4 acc = {bv, bv, bv, bv};
      #pragma unroll
      for (int kf = 0; kf < 4; ++kf) {
        short8 bfrag = *(const short8*)(&Wl[nlo][kf * 32 + q * 8]);
        acc = __builtin_amdgcn_mfma_f32_16x16x32_bf16(afrag[kf], bfrag, acc,
                                                      0, 0, 0);
      }
      // C layout: col = lane&15, row = q*4 + reg
      unsigned short* gp =
          gx + (size_t)(R0 + wv * 16 + q * 4) * G4 + n0 + m;
      #pragma unroll
      for (int r = 0; r < 4; ++r) gp[(size_t)r * G4] = f2bf(acc[r]);
    }
  }
}

// ---------------------------------------------------------------------------
// Kernel 2: reverse-time recurrence. One WG per batch element, 512 threads.
// Thread owns gate j = (tid&3)*128 + (tid>>2); W_hh row lives in 128 VGPRs
// (f32). h broadcast via double-buffered LDS; i/f/g/o recombined in-quad
// with 2 shfl_xor; ONE barrier per step.
// types: 0=i 1=f 2=g 3=o  (reference split order)
// ---------------------------------------------------------------------------
__global__ __launch_bounds__(512, 2) void lstm_rev(
    const unsigned short* __restrict__ gx,  // [S*B][512] bf16 (x-proj + bias)
    const float* __restrict__ timep,        // [S*B]
    const float* __restrict__ Whh,          // [512][128]
    const float* __restrict__ w_t,          // [128]
    const float* __restrict__ b_t,          // [128]
    float* __restrict__ out)                // S*B*H outputs, then h, then c
{
  __shared__ __align__(16) float hbuf[2][H_SZ];
  const int tid = threadIdx.x;
  const int b   = blockIdx.x;
  const int tt  = tid & 3;
  const int col = tid >> 2;
  const int j   = tt * 128 + col;

  // persistent weights: W_hh[j][0:128] in registers
  floatx4 w[32];
  const float* wrow = Whh + (size_t)j * H_SZ;
  #pragma unroll
  for (int q = 0; q < 32; ++q) w[q] = *(const floatx4*)(wrow + 4 * q);

  const float wt = w_t[col];
  const float bt = b_t[col];

  if (tid < H_SZ) hbuf[0][tid] = 0.0f;
  __syncthreads();

  const float LOG2E  = 1.4426950408889634f;
  const float kscale = (tt == 2) ? (-2.0f * LOG2E) : (-LOG2E);
  const float am     = (tt == 2) ? 2.0f : 1.0f;
  const float aa     = (tt == 2) ? -1.0f : 0.0f;
  const bool  odd    = (tt & 1) != 0;

  float c = 0.0f;
  {
    const size_t idx0 = (size_t)(S_LEN - 1) * B_SZ + b;
    float gxc = bf2f(gx[idx0 * G4 + j]);
    float tmc = timep[idx0];

    for (int t = S_LEN - 1; t >= 0; --t) {
      // prefetch next step's inputs (t=0: reload t=0, unused)
      const int tn = (t > 0) ? (t - 1) : 0;
      const size_t idxn = (size_t)tn * B_SZ + b;
      const float gxn = bf2f(gx[idxn * G4 + j]);
      const float tmn = timep[idxn];

      const int rb = (S_LEN - 1 - t) & 1;       // read-buffer parity
      const float* hr = hbuf[rb];

      // gate pre-activation: gx (+bias) + W_hh[j] . h   (4 ILP chains)
      float a0 = gxc, a1 = 0.0f, a2 = 0.0f, a3 = 0.0f;
      #pragma unroll
      for (int q = 0; q < 32; ++q) {
        floatx4 hv = *(const floatx4*)(hr + 4 * q);  // LDS broadcast read
        a0 = fmaf(w[q].x, hv.x, a0);
        a1 = fmaf(w[q].y, hv.y, a1);
        a2 = fmaf(w[q].z, hv.z, a2);
        a3 = fmaf(w[q].w, hv.w, a3);
      }
      const float acc = (a0 + a1) + (a2 + a3);

      // unified activation: i,f,o -> sigmoid; g -> tanh = 2*sigmoid(2x)-1
      const float e = __builtin_amdgcn_exp2f(acc * kscale);
      const float v = fmaf(am, __builtin_amdgcn_rcpf(1.0f + e), aa);

      // decay = exp(-relu(t*w_t + b_t))
      float z = fmaf(tmc, wt, bt);
      z = fmaxf(z, 0.0f);
      const float d = __builtin_amdgcn_exp2f(-LOG2E * z);

      // quad recombine: lanes (0,2) build i*g; lanes (1,3) build f*decay*c
      const float p2 = __shfl_xor(v, 2, 64);
      const float fv = (tt == 1) ? v : p2;      // f value on odd lanes
      const float r  = odd ? fv * (d * c) : v * p2;
      const float cn = r + __shfl_xor(r, 1, 64); // identical in all 4 lanes
      c = cn;

      const float e2 = __builtin_amdgcn_exp2f(-2.0f * LOG2E * cn);
      const float th = fmaf(2.0f, __builtin_amdgcn_rcpf(1.0f + e2), -1.0f);

      if (tt == 3) {                             // lane holding o
        const float h = v * th;
        hbuf[rb ^ 1][col] = h;
        out[((size_t)t * B_SZ + b) * H_SZ + col] = h;
        if (t == 0) {
          out[(size_t)S_LEN * B_SZ * H_SZ + (size_t)b * H_SZ + col] = h;
          out[(size_t)S_LEN * B_SZ * H_SZ + (size_t)B_SZ * H_SZ
              + (size_t)b * H_SZ + col] = c;
        }
      }
      __syncthreads();   // h writes visible; also fences next iter's writes
      gxc = gxn; tmc = tmn;
    }
  }
}

// ---------------------------------------------------------------------------
extern "C" void kernel_launch(void* const* d_in, const int* in_sizes, int n_in,
                              void* d_out, int out_size, void* d_ws, size_t ws_size,
                              hipStream_t stream) {
  const float* input = (const float*)d_in[0];   // (S,B,D)
  const float* timep = (const float*)d_in[1];   // (S,B,1)
  const float* W_ih  = (const float*)d_in[2];   // (4H,D)
  const float* W_hh  = (const float*)d_in[3];   // (4H,H)
  const float* bias  = (const float*)d_in[4];   // (4H,)
  const float* w_t   = (const float*)d_in[5];   // (H,)
  const float* b_t   = (const float*)d_in[6];   // (H,)
  float* out = (float*)d_out;

  unsigned short* gx = (unsigned short*)d_ws;   // needs 2048*64*512*2 = 128 MiB

  // 1) parallel x-projection (+bias) into bf16 scratch
  gx_gemm<<<dim3((S_LEN * B_SZ) / 64), dim3(256), 0, stream>>>(
      input, W_ih, bias, gx);

  // 2) sequential reverse recurrence, one WG per batch element
  lstm_rev<<<dim3(B_SZ), dim3(512), 0, stream>>>(
      gx, timep, W_hh, w_t, b_t, out);
}

// Round 2
// 1631.172 us; speedup vs baseline: 1.4837x; 1.4837x over previous
//
#include <hip/hip_runtime.h>

#define S_LEN 2048
#define B_SZ  64
#define D_IN  128
#define H_SZ  128
#define G4    512   // 4*H

typedef __attribute__((ext_vector_type(8))) short   short8;
typedef __attribute__((ext_vector_type(4))) float   floatx4;

// bf16 helpers (round-to-nearest-even)
__device__ __forceinline__ unsigned short f2bf(float f) {
  unsigned int u = __float_as_uint(f);
  u = (u + 0x7FFFu + ((u >> 16) & 1u)) >> 16;
  return (unsigned short)u;
}
__device__ __forceinline__ float bf2f(unsigned short s) {
  return __uint_as_float(((unsigned int)s) << 16);
}

// DPP quad_perm helper (VALU pipe — not LDS). CTRL: xor1=0xB1, xor2=0x4E.
template<int CTRL>
__device__ __forceinline__ float qperm(float v) {
  return __int_as_float(
      __builtin_amdgcn_mov_dpp(__float_as_int(v), CTRL, 0xF, 0xF, true));
}

// ---------------------------------------------------------------------------
// Kernel 1: gates_x[sb][n] = sum_k X[sb][k]*W_ih[n][k] + b[n], stored bf16.
// (unchanged from round 1 — ~6% of total time)
// ---------------------------------------------------------------------------
__global__ __launch_bounds__(256) void gx_gemm(
    const float* __restrict__ X,       // [S*B][128]
    const float* __restrict__ Wih,     // [512][128]
    const float* __restrict__ bias,    // [512]
    unsigned short* __restrict__ gx)   // [S*B][512] bf16
{
  __shared__ unsigned short Wl[128][136];
  const int tid  = threadIdx.x;
  const int lane = tid & 63;
  const int wv   = tid >> 6;
  const int R0   = blockIdx.x * 64;
  const int m    = lane & 15;
  const int q    = lane >> 4;

  short8 afrag[4];
  const float* xrow = X + (size_t)(R0 + wv * 16 + m) * D_IN;
  #pragma unroll
  for (int kf = 0; kf < 4; ++kf) {
    const int k0 = kf * 32 + q * 8;
    floatx4 v0 = *(const floatx4*)(xrow + k0);
    floatx4 v1 = *(const floatx4*)(xrow + k0 + 4);
    short8 a;
    a[0] = (short)f2bf(v0.x); a[1] = (short)f2bf(v0.y);
    a[2] = (short)f2bf(v0.z); a[3] = (short)f2bf(v0.w);
    a[4] = (short)f2bf(v1.x); a[5] = (short)f2bf(v1.y);
    a[6] = (short)f2bf(v1.z); a[7] = (short)f2bf(v1.w);
    afrag[kf] = a;
  }

  for (int nc = 0; nc < 4; ++nc) {
    __syncthreads();
    for (int i = tid; i < 128 * 32; i += 256) {
      const int row = i >> 5;
      const int c4  = (i & 31) * 4;
      floatx4 v = *(const floatx4*)(Wih + ((size_t)nc * 128 + row) * D_IN + c4);
      Wl[row][c4 + 0] = f2bf(v.x);
      Wl[row][c4 + 1] = f2bf(v.y);
      Wl[row][c4 + 2] = f2bf(v.z);
      Wl[row][c4 + 3] = f2bf(v.w);
    }
    __syncthreads();

    #pragma unroll
    for (int nt = 0; nt < 8; ++nt) {
      const int n0  = nc * 128 + nt * 16;
      const int nlo = nt * 16 + m;
      const float bv = bias[n0 + m];
      floatx4 acc = {bv, bv, bv, bv};
      #pragma unroll
      for (int kf = 0; kf < 4; ++kf) {
        short8 bfrag = *(const short8*)(&Wl[nlo][kf * 32 + q * 8]);
        acc = __builtin_amdgcn_mfma_f32_16x16x32_bf16(afrag[kf], bfrag, acc,
                                                      0, 0, 0);
      }
      unsigned short* gp =
          gx + (size_t)(R0 + wv * 16 + q * 4) * G4 + n0 + m;
      #pragma unroll
      for (int r = 0; r < 4; ++r) gp[(size_t)r * G4] = f2bf(acc[r]);
    }
  }
}

// ---------------------------------------------------------------------------
// Kernel 2: reverse-time recurrence. One WG per batch, 512 threads.
// NEW: quad k-split. Thread (tt,col) computes partial dots for ALL 4 gate
// types of `col` over k-chunks {i*16 + tt*4 .. +3 : i=0..7} (swizzled so the
// quad's b128 reads hit disjoint banks). 8 ds_read_b128/thread (was 32).
// Quad-reduce via DPP quad_perm (VALU pipe); recombination shuffles also DPP.
// types: 0=i 1=f 2=g 3=o
// ---------------------------------------------------------------------------
__global__ __launch_bounds__(512, 2) void lstm_rev(
    const unsigned short* __restrict__ gx,  // [S*B][512] bf16 (x-proj + bias)
    const float* __restrict__ timep,        // [S*B]
    const float* __restrict__ Whh,          // [512][128]
    const float* __restrict__ w_t,          // [128]
    const float* __restrict__ b_t,          // [128]
    float* __restrict__ out)                // S*B*H outputs, then h, then c
{
  __shared__ __align__(16) float hbuf[2][H_SZ];
  const int tid = threadIdx.x;
  const int b   = blockIdx.x;
  const int tt  = tid & 3;
  const int col = tid >> 2;
  const int j   = tt * 128 + col;   // gate this lane finalizes

  // Weights: w[ty][i] = W_hh[ty*128+col][i*16 + tt*4 .. +3]  (128 VGPRs)
  floatx4 w[4][8];
  #pragma unroll
  for (int ty = 0; ty < 4; ++ty) {
    const float* wrow = Whh + (size_t)(ty * 128 + col) * H_SZ + tt * 4;
    #pragma unroll
    for (int i = 0; i < 8; ++i) w[ty][i] = *(const floatx4*)(wrow + i * 16);
  }

  const float wt = w_t[col];
  const float bt = b_t[col];

  if (tid < H_SZ) hbuf[0][tid] = 0.0f;
  __syncthreads();

  const float LOG2E  = 1.4426950408889634f;
  const float kscale = (tt == 2) ? (-2.0f * LOG2E) : (-LOG2E);
  const float am     = (tt == 2) ? 2.0f : 1.0f;
  const float aa     = (tt == 2) ? -1.0f : 0.0f;
  const bool  odd    = (tt & 1) != 0;

  float c = 0.0f;
  {
    const size_t idx0 = (size_t)(S_LEN - 1) * B_SZ + b;
    float gxc = bf2f(gx[idx0 * G4 + j]);
    float tmc = timep[idx0];

    for (int t = S_LEN - 1; t >= 0; --t) {
      // prefetch next step's inputs
      const int tn = (t > 0) ? (t - 1) : 0;
      const size_t idxn = (size_t)tn * B_SZ + b;
      const float gxn = bf2f(gx[idxn * G4 + j]);
      const float tmn = timep[idxn];

      const int rb = (S_LEN - 1 - t) & 1;

      // this thread's quarter of h: chunks at k = i*16 + tt*4
      floatx4 hv[8];
      #pragma unroll
      for (int i = 0; i < 8; ++i)
        hv[i] = *(const floatx4*)(&hbuf[rb][i * 16 + tt * 4]);

      // 4 types × 2 sub-accumulators (8 ILP chains of depth 16)
      float p0a = 0.f, p0b = 0.f, p1a = 0.f, p1b = 0.f;
      float p2a = 0.f, p2b = 0.f, p3a = 0.f, p3b = 0.f;
      #pragma unroll
      for (int i = 0; i < 8; i += 2) {
        p0a = fmaf(w[0][i].x, hv[i].x, p0a);
        p0a = fmaf(w[0][i].y, hv[i].y, p0a);
        p0a = fmaf(w[0][i].z, hv[i].z, p0a);
        p0a = fmaf(w[0][i].w, hv[i].w, p0a);
        p0b = fmaf(w[0][i+1].x, hv[i+1].x, p0b);
        p0b = fmaf(w[0][i+1].y, hv[i+1].y, p0b);
        p0b = fmaf(w[0][i+1].z, hv[i+1].z, p0b);
        p0b = fmaf(w[0][i+1].w, hv[i+1].w, p0b);
        p1a = fmaf(w[1][i].x, hv[i].x, p1a);
        p1a = fmaf(w[1][i].y, hv[i].y, p1a);
        p1a = fmaf(w[1][i].z, hv[i].z, p1a);
        p1a = fmaf(w[1][i].w, hv[i].w, p1a);
        p1b = fmaf(w[1][i+1].x, hv[i+1].x, p1b);
        p1b = fmaf(w[1][i+1].y, hv[i+1].y, p1b);
        p1b = fmaf(w[1][i+1].z, hv[i+1].z, p1b);
        p1b = fmaf(w[1][i+1].w, hv[i+1].w, p1b);
        p2a = fmaf(w[2][i].x, hv[i].x, p2a);
        p2a = fmaf(w[2][i].y, hv[i].y, p2a);
        p2a = fmaf(w[2][i].z, hv[i].z, p2a);
        p2a = fmaf(w[2][i].w, hv[i].w, p2a);
        p2b = fmaf(w[2][i+1].x, hv[i+1].x, p2b);
        p2b = fmaf(w[2][i+1].y, hv[i+1].y, p2b);
        p2b = fmaf(w[2][i+1].z, hv[i+1].z, p2b);
        p2b = fmaf(w[2][i+1].w, hv[i+1].w, p2b);
        p3a = fmaf(w[3][i].x, hv[i].x, p3a);
        p3a = fmaf(w[3][i].y, hv[i].y, p3a);
        p3a = fmaf(w[3][i].z, hv[i].z, p3a);
        p3a = fmaf(w[3][i].w, hv[i].w, p3a);
        p3b = fmaf(w[3][i+1].x, hv[i+1].x, p3b);
        p3b = fmaf(w[3][i+1].y, hv[i+1].y, p3b);
        p3b = fmaf(w[3][i+1].z, hv[i+1].z, p3b);
        p3b = fmaf(w[3][i+1].w, hv[i+1].w, p3b);
      }
      float a0 = p0a + p0b, a1 = p1a + p1b, a2 = p2a + p2b, a3 = p3a + p3b;

      // quad reduction per type — DPP (VALU), no LDS traffic
      a0 += qperm<0xB1>(a0); a0 += qperm<0x4E>(a0);
      a1 += qperm<0xB1>(a1); a1 += qperm<0x4E>(a1);
      a2 += qperm<0xB1>(a2); a2 += qperm<0x4E>(a2);
      a3 += qperm<0xB1>(a3); a3 += qperm<0x4E>(a3);

      // lane tt keeps type tt's full dot, add x-projection (+bias)
      float acc = (tt & 1) ? ((tt & 2) ? a3 : a1) : ((tt & 2) ? a2 : a0);
      acc += gxc;

      // unified activation: i,f,o -> sigmoid; g -> tanh = 2*sigmoid(2x)-1
      const float e = __builtin_amdgcn_exp2f(acc * kscale);
      const float v = fmaf(am, __builtin_amdgcn_rcpf(1.0f + e), aa);

      // decay = exp(-relu(t*w_t + b_t))
      float z = fmaf(tmc, wt, bt);
      z = fmaxf(z, 0.0f);
      const float d = __builtin_amdgcn_exp2f(-LOG2E * z);

      // quad recombine (DPP): lanes (0,2) build i*g; lanes (1,3) f*decay*c
      const float p2 = qperm<0x4E>(v);
      const float fv = (tt == 1) ? v : p2;
      const float r  = odd ? fv * (d * c) : v * p2;
      const float cn = r + qperm<0xB1>(r);   // identical across the quad
      c = cn;

      const float e2 = __builtin_amdgcn_exp2f(-2.0f * LOG2E * cn);
      const float th = fmaf(2.0f, __builtin_amdgcn_rcpf(1.0f + e2), -1.0f);

      if (tt == 3) {                         // lane holding o
        const float h = v * th;
        hbuf[rb ^ 1][col] = h;
        out[((size_t)t * B_SZ + b) * H_SZ + col] = h;
        if (t == 0) {
          out[(size_t)S_LEN * B_SZ * H_SZ + (size_t)b * H_SZ + col] = h;
          out[(size_t)S_LEN * B_SZ * H_SZ + (size_t)B_SZ * H_SZ
              + (size_t)b * H_SZ + col] = c;
        }
      }
      __syncthreads();   // h writes visible before next step's reads
      gxc = gxn; tmc = tmn;
    }
  }
}

// ---------------------------------------------------------------------------
extern "C" void kernel_launch(void* const* d_in, const int* in_sizes, int n_in,
                              void* d_out, int out_size, void* d_ws, size_t ws_size,
                              hipStream_t stream) {
  const float* input = (const float*)d_in[0];   // (S,B,D)
  const float* timep = (const float*)d_in[1];   // (S,B,1)
  const float* W_ih  = (const float*)d_in[2];   // (4H,D)
  const float* W_hh  = (const float*)d_in[3];   // (4H,H)
  const float* bias  = (const float*)d_in[4];   // (4H,)
  const float* w_t   = (const float*)d_in[5];   // (H,)
  const float* b_t   = (const float*)d_in[6];   // (H,)
  float* out = (float*)d_out;

  unsigned short* gx = (unsigned short*)d_ws;   // 2048*64*512*2 = 128 MiB

  gx_gemm<<<dim3((S_LEN * B_SZ) / 64), dim3(256), 0, stream>>>(
      input, W_ih, bias, gx);

  lstm_rev<<<dim3(B_SZ), dim3(512), 0, stream>>>(
      gx, timep, W_hh, w_t, b_t, out);
}

// Round 3
// 1367.327 us; speedup vs baseline: 1.7700x; 1.1930x over previous
//
#include <hip/hip_runtime.h>

#define S_LEN 2048
#define B_SZ  64
#define D_IN  128
#define H_SZ  128
#define G4    512   // 4*H

typedef __attribute__((ext_vector_type(4))) float     floatx4;
typedef __attribute__((ext_vector_type(8))) _Float16  half8;
typedef __attribute__((ext_vector_type(2))) _Float16  half2_t;

union H8 { half8 v; half2_t p[4]; };

// DPP quad_perm helper (VALU pipe). CTRL: xor1=0xB1, xor2=0x4E.
template<int CTRL>
__device__ __forceinline__ float qperm(float v) {
  return __int_as_float(
      __builtin_amdgcn_mov_dpp(__float_as_int(v), CTRL, 0xF, 0xF, true));
}

// ---------------------------------------------------------------------------
// Kernel 1: gates_x[sb][n] = sum_k X[sb][k]*W_ih[n][k] + b[n], stored f16.
// MFMA f32_16x16x32_f16 (f16 inputs: 8x less rounding error than bf16).
// ---------------------------------------------------------------------------
__global__ __launch_bounds__(256) void gx_gemm(
    const float* __restrict__ X,       // [S*B][128]
    const float* __restrict__ Wih,     // [512][128]
    const float* __restrict__ bias,    // [512]
    _Float16* __restrict__ gx)         // [S*B][512] f16
{
  __shared__ _Float16 Wl[128][136];    // 136*2=272 B rows (16B-aligned)
  const int tid  = threadIdx.x;
  const int lane = tid & 63;
  const int wv   = tid >> 6;
  const int R0   = blockIdx.x * 64;
  const int m    = lane & 15;
  const int q    = lane >> 4;

  half8 afrag[4];
  const float* xrow = X + (size_t)(R0 + wv * 16 + m) * D_IN;
  #pragma unroll
  for (int kf = 0; kf < 4; ++kf) {
    const int k0 = kf * 32 + q * 8;
    floatx4 v0 = *(const floatx4*)(xrow + k0);
    floatx4 v1 = *(const floatx4*)(xrow + k0 + 4);
    half8 a;
    a[0] = (_Float16)v0.x; a[1] = (_Float16)v0.y;
    a[2] = (_Float16)v0.z; a[3] = (_Float16)v0.w;
    a[4] = (_Float16)v1.x; a[5] = (_Float16)v1.y;
    a[6] = (_Float16)v1.z; a[7] = (_Float16)v1.w;
    afrag[kf] = a;
  }

  for (int nc = 0; nc < 4; ++nc) {
    __syncthreads();
    for (int i = tid; i < 128 * 32; i += 256) {
      const int row = i >> 5;
      const int c4  = (i & 31) * 4;
      floatx4 v = *(const floatx4*)(Wih + ((size_t)nc * 128 + row) * D_IN + c4);
      Wl[row][c4 + 0] = (_Float16)v.x;
      Wl[row][c4 + 1] = (_Float16)v.y;
      Wl[row][c4 + 2] = (_Float16)v.z;
      Wl[row][c4 + 3] = (_Float16)v.w;
    }
    __syncthreads();

    #pragma unroll
    for (int nt = 0; nt < 8; ++nt) {
      const int n0  = nc * 128 + nt * 16;
      const int nlo = nt * 16 + m;
      const float bv = bias[n0 + m];
      floatx4 acc = {bv, bv, bv, bv};
      #pragma unroll
      for (int kf = 0; kf < 4; ++kf) {
        half8 bfrag = *(const half8*)(&Wl[nlo][kf * 32 + q * 8]);
        acc = __builtin_amdgcn_mfma_f32_16x16x32_f16(afrag[kf], bfrag, acc,
                                                     0, 0, 0);
      }
      // C layout: col = lane&15, row = q*4 + reg
      _Float16* gp = gx + (size_t)(R0 + wv * 16 + q * 4) * G4 + n0 + m;
      #pragma unroll
      for (int r = 0; r < 4; ++r) gp[(size_t)r * G4] = (_Float16)acc[r];
    }
  }
}

// ---------------------------------------------------------------------------
// Kernel 2: reverse-time recurrence. One WG per batch, 512 threads.
// NEW vs round 2: f16 data path. W_hh held as f16 pairs (64 VGPRs), h stored
// f16 in LDS (4 ds_read_b128/thread, was 8), dot via v_dot2_f32_f16
// (64 instr, was 128 fmac). c stays f32. DPP quad reduce/recombine.
// types: 0=i 1=f 2=g 3=o
// ---------------------------------------------------------------------------
__global__ __launch_bounds__(512, 2) void lstm_rev(
    const _Float16* __restrict__ gx,        // [S*B][512] f16 (x-proj + bias)
    const float* __restrict__ timep,        // [S*B]
    const float* __restrict__ Whh,          // [512][128]
    const float* __restrict__ w_t,          // [128]
    const float* __restrict__ b_t,          // [128]
    float* __restrict__ out)                // S*B*H outputs, then h, then c
{
  __shared__ __align__(16) _Float16 hbuf[2][H_SZ];
  const int tid = threadIdx.x;
  const int b   = blockIdx.x;
  const int tt  = tid & 3;
  const int col = tid >> 2;
  const int j   = tt * 128 + col;   // gate this lane finalizes

  // Weights as f16: w[ty][i] = W_hh[ty*128+col][i*32 + tt*8 .. +7]
  half8 w[4][4];                    // 64 VGPRs
  #pragma unroll
  for (int ty = 0; ty < 4; ++ty) {
    const float* wrow = Whh + (size_t)(ty * 128 + col) * H_SZ + tt * 8;
    #pragma unroll
    for (int i = 0; i < 4; ++i) {
      floatx4 v0 = *(const floatx4*)(wrow + i * 32);
      floatx4 v1 = *(const floatx4*)(wrow + i * 32 + 4);
      half8 hh;
      hh[0] = (_Float16)v0.x; hh[1] = (_Float16)v0.y;
      hh[2] = (_Float16)v0.z; hh[3] = (_Float16)v0.w;
      hh[4] = (_Float16)v1.x; hh[5] = (_Float16)v1.y;
      hh[6] = (_Float16)v1.z; hh[7] = (_Float16)v1.w;
      w[ty][i] = hh;
    }
  }

  const float wt = w_t[col];
  const float bt = b_t[col];

  if (tid < H_SZ) hbuf[0][tid] = (_Float16)0.0f;
  __syncthreads();

  const float LOG2E  = 1.4426950408889634f;
  const float kscale = (tt == 2) ? (-2.0f * LOG2E) : (-LOG2E);
  const float am     = (tt == 2) ? 2.0f : 1.0f;
  const float aa     = (tt == 2) ? -1.0f : 0.0f;
  const bool  odd    = (tt & 1) != 0;

  float c = 0.0f;
  {
    const size_t idx0 = (size_t)(S_LEN - 1) * B_SZ + b;
    float gxc = (float)gx[idx0 * G4 + j];
    float tmc = timep[idx0];

    for (int t = S_LEN - 1; t >= 0; --t) {
      // prefetch next step's inputs
      const int tn = (t > 0) ? (t - 1) : 0;
      const size_t idxn = (size_t)tn * B_SZ + b;
      const float gxn = (float)gx[idxn * G4 + j];
      const float tmn = timep[idxn];

      const int rb = (S_LEN - 1 - t) & 1;

      // this thread's quarter of h (f16): chunks at k = i*32 + tt*8
      H8 hv[4];
      #pragma unroll
      for (int i = 0; i < 4; ++i)
        hv[i].v = *(const half8*)(&hbuf[rb][i * 32 + tt * 8]);

      // 4 types x 2 sub-accumulators, 64 fdot2 (2 MACs each)
      float acc[4][2] = {{0.f,0.f},{0.f,0.f},{0.f,0.f},{0.f,0.f}};
      #pragma unroll
      for (int i = 0; i < 4; ++i) {
        H8 wu0; wu0.v = w[0][i];
        H8 wu1; wu1.v = w[1][i];
        H8 wu2; wu2.v = w[2][i];
        H8 wu3; wu3.v = w[3][i];
        #pragma unroll
        for (int p = 0; p < 4; ++p) {
          const int ch = p >> 1;   // split pairs across 2 chains
          acc[0][ch] = __builtin_amdgcn_fdot2(hv[i].p[p], wu0.p[p],
                                              acc[0][ch], false);
          acc[1][ch] = __builtin_amdgcn_fdot2(hv[i].p[p], wu1.p[p],
                                              acc[1][ch], false);
          acc[2][ch] = __builtin_amdgcn_fdot2(hv[i].p[p], wu2.p[p],
                                              acc[2][ch], false);
          acc[3][ch] = __builtin_amdgcn_fdot2(hv[i].p[p], wu3.p[p],
                                              acc[3][ch], false);
        }
      }
      float a0 = acc[0][0] + acc[0][1];
      float a1 = acc[1][0] + acc[1][1];
      float a2 = acc[2][0] + acc[2][1];
      float a3 = acc[3][0] + acc[3][1];

      // quad reduction per type — DPP (VALU pipe)
      a0 += qperm<0xB1>(a0); a0 += qperm<0x4E>(a0);
      a1 += qperm<0xB1>(a1); a1 += qperm<0x4E>(a1);
      a2 += qperm<0xB1>(a2); a2 += qperm<0x4E>(a2);
      a3 += qperm<0xB1>(a3); a3 += qperm<0x4E>(a3);

      // lane tt keeps type tt's full dot, add x-projection (+bias)
      float pre = (tt & 1) ? ((tt & 2) ? a3 : a1) : ((tt & 2) ? a2 : a0);
      pre += gxc;

      // unified activation: i,f,o -> sigmoid; g -> tanh = 2*sigmoid(2x)-1
      const float e = __builtin_amdgcn_exp2f(pre * kscale);
      const float v = fmaf(am, __builtin_amdgcn_rcpf(1.0f + e), aa);

      // decay = exp(-relu(t*w_t + b_t))
      float z = fmaf(tmc, wt, bt);
      z = fmaxf(z, 0.0f);
      const float d = __builtin_amdgcn_exp2f(-LOG2E * z);

      // quad recombine (DPP): lanes (0,2) build i*g; lanes (1,3) f*decay*c
      const float p2 = qperm<0x4E>(v);
      const float fv = (tt == 1) ? v : p2;
      const float r  = odd ? fv * (d * c) : v * p2;
      const float cn = r + qperm<0xB1>(r);   // identical across the quad
      c = cn;

      const float e2 = __builtin_amdgcn_exp2f(-2.0f * LOG2E * cn);
      const float th = fmaf(2.0f, __builtin_amdgcn_rcpf(1.0f + e2), -1.0f);

      if (tt == 3) {                         // lane holding o
        const float h = v * th;
        hbuf[rb ^ 1][col] = (_Float16)h;
        out[((size_t)t * B_SZ + b) * H_SZ + col] = h;
        if (t == 0) {
          out[(size_t)S_LEN * B_SZ * H_SZ + (size_t)b * H_SZ + col] = h;
          out[(size_t)S_LEN * B_SZ * H_SZ + (size_t)B_SZ * H_SZ
              + (size_t)b * H_SZ + col] = c;
        }
      }
      __syncthreads();   // h writes visible before next step's reads
      gxc = gxn; tmc = tmn;
    }
  }
}

// ---------------------------------------------------------------------------
extern "C" void kernel_launch(void* const* d_in, const int* in_sizes, int n_in,
                              void* d_out, int out_size, void* d_ws, size_t ws_size,
                              hipStream_t stream) {
  const float* input = (const float*)d_in[0];   // (S,B,D)
  const float* timep = (const float*)d_in[1];   // (S,B,1)
  const float* W_ih  = (const float*)d_in[2];   // (4H,D)
  const float* W_hh  = (const float*)d_in[3];   // (4H,H)
  const float* bias  = (const float*)d_in[4];   // (4H,)
  const float* w_t   = (const float*)d_in[5];   // (H,)
  const float* b_t   = (const float*)d_in[6];   // (H,)
  float* out = (float*)d_out;

  _Float16* gx = (_Float16*)d_ws;   // 2048*64*512*2 = 128 MiB

  gx_gemm<<<dim3((S_LEN * B_SZ) / 64), dim3(256), 0, stream>>>(
      input, W_ih, bias, gx);

  lstm_rev<<<dim3(B_SZ), dim3(512), 0, stream>>>(
      gx, timep, W_hh, w_t, b_t, out);
}

// Round 4
// 1333.030 us; speedup vs baseline: 1.8155x; 1.0257x over previous
//
#include <hip/hip_runtime.h>

#define S_LEN 2048
#define B_SZ  64
#define D_IN  128
#define H_SZ  128
#define G4    512   // 4*H

typedef __attribute__((ext_vector_type(4))) float     floatx4;
typedef __attribute__((ext_vector_type(8))) _Float16  half8;
typedef __attribute__((ext_vector_type(2))) _Float16  half2_t;

// DPP quad_perm helper (VALU pipe). CTRL: xor1=0xB1, xor2=0x4E.
template<int CTRL>
__device__ __forceinline__ float qperm(float v) {
  return __int_as_float(
      __builtin_amdgcn_mov_dpp(__float_as_int(v), CTRL, 0xF, 0xF, true));
}

// half2 extraction from half8 — register aliasing, no union round-trip
template<int P>
__device__ __forceinline__ half2_t h2ext(half8 v) {
  return __builtin_shufflevector(v, v, 2 * P, 2 * P + 1);
}

// Workgroup barrier that drains ONLY lgkmcnt (LDS), leaving global loads/
// stores (vmcnt) in flight. __syncthreads() would drain vmcnt(0) each step.
__device__ __forceinline__ void lds_barrier() {
  asm volatile("s_waitcnt lgkmcnt(0)\n\ts_barrier" ::: "memory");
}

// ---------------------------------------------------------------------------
// Kernel 1: gates_x[sb][n] = (sum_k X[sb][k]*W_ih[n][k] + b[n]) * sc(type),
// stored f16.  sc = -log2e for i,f,o; -2log2e for g (folds the sigmoid/tanh
// exp2 scaling into the data so lstm_rev's activation chain is shorter).
// 256 rows/WG: W chunk staged ONCE per 4 row-groups (was once per 1).
// ---------------------------------------------------------------------------
__global__ __launch_bounds__(256) void gx_gemm(
    const float* __restrict__ X,       // [S*B][128]
    const float* __restrict__ Wih,     // [512][128]
    const float* __restrict__ bias,    // [512]
    _Float16* __restrict__ gx)         // [S*B][512] f16, pre-scaled
{
  __shared__ _Float16 Wl[128][136];
  const int tid  = threadIdx.x;
  const int lane = tid & 63;
  const int wv   = tid >> 6;
  const int R0   = blockIdx.x * 256;
  const int m    = lane & 15;
  const int q    = lane >> 4;

  const float LOG2E = 1.4426950408889634f;

  // A-fragments for 4 row-groups of 64 rows each
  half8 afrag[4][4];
  #pragma unroll
  for (int rg = 0; rg < 4; ++rg) {
    const float* xrow = X + (size_t)(R0 + rg * 64 + wv * 16 + m) * D_IN;
    #pragma unroll
    for (int kf = 0; kf < 4; ++kf) {
      const int k0 = kf * 32 + q * 8;
      floatx4 v0 = *(const floatx4*)(xrow + k0);
      floatx4 v1 = *(const floatx4*)(xrow + k0 + 4);
      half8 a;
      a[0] = (_Float16)v0.x; a[1] = (_Float16)v0.y;
      a[2] = (_Float16)v0.z; a[3] = (_Float16)v0.w;
      a[4] = (_Float16)v1.x; a[5] = (_Float16)v1.y;
      a[6] = (_Float16)v1.z; a[7] = (_Float16)v1.w;
      afrag[rg][kf] = a;
    }
  }

  for (int nc = 0; nc < 4; ++nc) {      // gate-type chunk (128 gate rows)
    const float sc = (nc == 2) ? (-2.0f * LOG2E) : (-LOG2E);
    __syncthreads();
    for (int i = tid; i < 128 * 32; i += 256) {
      const int row = i >> 5;
      const int c4  = (i & 31) * 4;
      floatx4 v = *(const floatx4*)(Wih + ((size_t)nc * 128 + row) * D_IN + c4);
      Wl[row][c4 + 0] = (_Float16)v.x;
      Wl[row][c4 + 1] = (_Float16)v.y;
      Wl[row][c4 + 2] = (_Float16)v.z;
      Wl[row][c4 + 3] = (_Float16)v.w;
    }
    __syncthreads();

    #pragma unroll
    for (int nt = 0; nt < 8; ++nt) {
      const int n0  = nc * 128 + nt * 16;
      const int nlo = nt * 16 + m;
      const float bv = bias[n0 + m];
      half8 bfrag[4];
      #pragma unroll
      for (int kf = 0; kf < 4; ++kf)
        bfrag[kf] = *(const half8*)(&Wl[nlo][kf * 32 + q * 8]);
      #pragma unroll
      for (int rg = 0; rg < 4; ++rg) {
        floatx4 acc = {bv, bv, bv, bv};
        #pragma unroll
        for (int kf = 0; kf < 4; ++kf)
          acc = __builtin_amdgcn_mfma_f32_16x16x32_f16(afrag[rg][kf],
                                                       bfrag[kf], acc, 0, 0, 0);
        // C layout: col = lane&15, row = q*4 + reg
        _Float16* gp =
            gx + (size_t)(R0 + rg * 64 + wv * 16 + q * 4) * G4 + n0 + m;
        #pragma unroll
        for (int r = 0; r < 4; ++r)
          gp[(size_t)r * G4] = (_Float16)(acc[r] * sc);
      }
    }
  }
}

// ---------------------------------------------------------------------------
// Kernel 2: reverse-time recurrence. One WG per batch, 512 threads.
// W_hh pre-scaled by -log2e/-2log2e at load (gate exp2 needs no mul).
// 2x unrolled (static LDS parity), pointer-stepped, lgkm-only barrier.
// types: 0=i 1=f 2=g 3=o
// ---------------------------------------------------------------------------
#define LSTM_STEP(HR, HW, TCUR, GPN, TPN)                                     \
  {                                                                           \
    const float gxn = (float)*(GPN);                                          \
    const float tmn = *(TPN);                                                 \
    half8 hv0 = *(const half8*)((HR) + 0 * 32 + tt * 8);                      \
    half8 hv1 = *(const half8*)((HR) + 1 * 32 + tt * 8);                      \
    half8 hv2 = *(const half8*)((HR) + 2 * 32 + tt * 8);                      \
    half8 hv3 = *(const half8*)((HR) + 3 * 32 + tt * 8);                      \
    float q0a = 0.f, q0b = 0.f, q1a = 0.f, q1b = 0.f;                         \
    float q2a = 0.f, q2b = 0.f, q3a = 0.f, q3b = 0.f;                         \
    DOT8(0, hv0); DOT8(1, hv1); DOT8(2, hv2); DOT8(3, hv3);                   \
    float a0 = q0a + q0b, a1 = q1a + q1b, a2 = q2a + q2b, a3 = q3a + q3b;     \
    a0 += qperm<0xB1>(a0); a1 += qperm<0xB1>(a1);                             \
    a2 += qperm<0xB1>(a2); a3 += qperm<0xB1>(a3);                             \
    a0 += qperm<0x4E>(a0); a1 += qperm<0x4E>(a1);                             \
    a2 += qperm<0x4E>(a2); a3 += qperm<0x4E>(a3);                             \
    float pre = (tt & 1) ? ((tt & 2) ? a3 : a1) : ((tt & 2) ? a2 : a0);       \
    pre += gxc;  /* pre is already scaled by -log2e (or -2log2e for g) */     \
    const float e = __builtin_amdgcn_exp2f(pre);                              \
    const float v = fmaf(am, __builtin_amdgcn_rcpf(1.0f + e), aa);            \
    float z = fmaf(tmc, wt, bt);            /* = -log2e*(t*w_t+b_t) */        \
    z = fminf(z, 0.0f);                     /* -log2e*relu(.) */              \
    const float d = __builtin_amdgcn_exp2f(z);                                \
    const float p2 = qperm<0x4E>(v);                                          \
    const float fv = (tt == 1) ? v : p2;                                      \
    const float r  = odd ? fv * (d * c) : v * p2;                             \
    const float cn = r + qperm<0xB1>(r);                                      \
    c = cn;                                                                   \
    const float e2 = __builtin_amdgcn_exp2f(-2.0f * LOG2E * cn);              \
    const float th = fmaf(2.0f, __builtin_amdgcn_rcpf(1.0f + e2), -1.0f);     \
    if (tt == 3) {                                                            \
      const float h = v * th;                                                 \
      (HW)[col] = (_Float16)h;                                                \
      op[0] = h;                                                              \
      if ((TCUR) == 0) {                                                      \
        out[(size_t)S_LEN * B_SZ * H_SZ + (size_t)b * H_SZ + col] = h;        \
        out[(size_t)S_LEN * B_SZ * H_SZ + (size_t)B_SZ * H_SZ                 \
            + (size_t)b * H_SZ + col] = c;                                    \
      }                                                                       \
    }                                                                         \
    lds_barrier();                                                            \
    gxc = gxn; tmc = tmn;                                                     \
    gp = (GPN); tp = (TPN); op -= (size_t)B_SZ * H_SZ;                        \
  }

#define DOT8(I, HV)                                                           \
  {                                                                           \
    q0a = __builtin_amdgcn_fdot2(h2ext<0>(HV), h2ext<0>(w[0][I]), q0a, false);\
    q1a = __builtin_amdgcn_fdot2(h2ext<0>(HV), h2ext<0>(w[1][I]), q1a, false);\
    q2a = __builtin_amdgcn_fdot2(h2ext<0>(HV), h2ext<0>(w[2][I]), q2a, false);\
    q3a = __builtin_amdgcn_fdot2(h2ext<0>(HV), h2ext<0>(w[3][I]), q3a, false);\
    q0a = __builtin_amdgcn_fdot2(h2ext<1>(HV), h2ext<1>(w[0][I]), q0a, false);\
    q1a = __builtin_amdgcn_fdot2(h2ext<1>(HV), h2ext<1>(w[1][I]), q1a, false);\
    q2a = __builtin_amdgcn_fdot2(h2ext<1>(HV), h2ext<1>(w[2][I]), q2a, false);\
    q3a = __builtin_amdgcn_fdot2(h2ext<1>(HV), h2ext<1>(w[3][I]), q3a, false);\
    q0b = __builtin_amdgcn_fdot2(h2ext<2>(HV), h2ext<2>(w[0][I]), q0b, false);\
    q1b = __builtin_amdgcn_fdot2(h2ext<2>(HV), h2ext<2>(w[1][I]), q1b, false);\
    q2b = __builtin_amdgcn_fdot2(h2ext<2>(HV), h2ext<2>(w[2][I]), q2b, false);\
    q3b = __builtin_amdgcn_fdot2(h2ext<2>(HV), h2ext<2>(w[3][I]), q3b, false);\
    q0b = __builtin_amdgcn_fdot2(h2ext<3>(HV), h2ext<3>(w[0][I]), q0b, false);\
    q1b = __builtin_amdgcn_fdot2(h2ext<3>(HV), h2ext<3>(w[1][I]), q1b, false);\
    q2b = __builtin_amdgcn_fdot2(h2ext<3>(HV), h2ext<3>(w[2][I]), q2b, false);\
    q3b = __builtin_amdgcn_fdot2(h2ext<3>(HV), h2ext<3>(w[3][I]), q3b, false);\
  }

__global__ __launch_bounds__(512, 2) void lstm_rev(
    const _Float16* __restrict__ gx,        // [S*B][512] f16, pre-scaled
    const float* __restrict__ timep,        // [S*B]
    const float* __restrict__ Whh,          // [512][128]
    const float* __restrict__ w_tp,         // [128]
    const float* __restrict__ b_tp,         // [128]
    float* __restrict__ out)                // S*B*H outputs, then h, then c
{
  __shared__ __align__(16) _Float16 hbuf[2][H_SZ];
  const int tid = threadIdx.x;
  const int b   = blockIdx.x;
  const int tt  = tid & 3;
  const int col = tid >> 2;
  const int j   = tt * 128 + col;

  const float LOG2E = 1.4426950408889634f;

  // Pre-scaled f16 weights: w[ty][i] = sc(ty) * W_hh[ty*128+col][i*32+tt*8..+7]
  half8 w[4][4];                    // 64 VGPRs
  #pragma unroll
  for (int ty = 0; ty < 4; ++ty) {
    const float sc = (ty == 2) ? (-2.0f * LOG2E) : (-LOG2E);
    const float* wrow = Whh + (size_t)(ty * 128 + col) * H_SZ + tt * 8;
    #pragma unroll
    for (int i = 0; i < 4; ++i) {
      floatx4 v0 = *(const floatx4*)(wrow + i * 32);
      floatx4 v1 = *(const floatx4*)(wrow + i * 32 + 4);
      half8 hh;
      hh[0] = (_Float16)(v0.x * sc); hh[1] = (_Float16)(v0.y * sc);
      hh[2] = (_Float16)(v0.z * sc); hh[3] = (_Float16)(v0.w * sc);
      hh[4] = (_Float16)(v1.x * sc); hh[5] = (_Float16)(v1.y * sc);
      hh[6] = (_Float16)(v1.z * sc); hh[7] = (_Float16)(v1.w * sc);
      w[ty][i] = hh;
    }
  }

  const float wt = -LOG2E * w_tp[col];
  const float bt = -LOG2E * b_tp[col];

  const float kscale = (tt == 2) ? (-2.0f * LOG2E) : (-LOG2E);
  (void)kscale;
  const float am  = (tt == 2) ? 2.0f : 1.0f;
  const float aa  = (tt == 2) ? -1.0f : 0.0f;
  const bool  odd = (tt & 1) != 0;

  if (tid < H_SZ) hbuf[0][tid] = (_Float16)0.0f;
  __syncthreads();

  const _Float16* gp = gx + ((size_t)(S_LEN - 1) * B_SZ + b) * G4 + j;
  const float*    tp = timep + (size_t)(S_LEN - 1) * B_SZ + b;
  float*          op = out + ((size_t)(S_LEN - 1) * B_SZ + b) * H_SZ + col;

  float gxc = (float)*gp;
  float tmc = *tp;
  float c = 0.0f;

  _Float16* h0 = &hbuf[0][0];
  _Float16* h1 = &hbuf[1][0];

  for (int t = S_LEN - 1; t > 0; t -= 2) {
    // substep A: step t, read hbuf[0], write hbuf[1]; prefetch t-1 (>=0 ok)
    LSTM_STEP(h0, h1, t, gp - (size_t)B_SZ * G4, tp - B_SZ);
    // substep B: step t-1, read hbuf[1], write hbuf[0]; prefetch t-2 (clamped)
    {
      const _Float16* gpn = (t > 1) ? gp - (size_t)B_SZ * G4 : gp;
      const float*    tpn = (t > 1) ? tp - B_SZ : tp;
      LSTM_STEP(h1, h0, t - 1, gpn, tpn);
    }
  }
}

// ---------------------------------------------------------------------------
extern "C" void kernel_launch(void* const* d_in, const int* in_sizes, int n_in,
                              void* d_out, int out_size, void* d_ws, size_t ws_size,
                              hipStream_t stream) {
  const float* input = (const float*)d_in[0];   // (S,B,D)
  const float* timep = (const float*)d_in[1];   // (S,B,1)
  const float* W_ih  = (const float*)d_in[2];   // (4H,D)
  const float* W_hh  = (const float*)d_in[3];   // (4H,H)
  const float* bias  = (const float*)d_in[4];   // (4H,)
  const float* w_t   = (const float*)d_in[5];   // (H,)
  const float* b_t   = (const float*)d_in[6];   // (H,)
  float* out = (float*)d_out;

  _Float16* gx = (_Float16*)d_ws;   // 2048*64*512*2 = 128 MiB

  gx_gemm<<<dim3((S_LEN * B_SZ) / 256), dim3(256), 0, stream>>>(
      input, W_ih, bias, gx);

  lstm_rev<<<dim3(B_SZ), dim3(512), 0, stream>>>(
      gx, timep, W_hh, w_t, b_t, out);
}